// Round 11
// baseline (275.670 us; speedup 1.0000x reference)
//
#include <hip/hip_runtime.h>

// Problem constants
#define D 32
#define K 8
#define NPAIR 36
#define PROWS 576              // packed (4-padded triangular) floats per matrix

// ws layout (float offsets)
#define PMOFF 0                // packed invLc, 8 x 576
#define WOFF 4608              // w_k = invLc_k mu_k, 8 x 32
#define C2OFF 4864             // (c'_t - cmax) * log2(e), 36
#define CMAXOFF 4900
#define LCOFF 4928             // Lc (cholesky factors), 8 x 32 x 32, upper zeroed
#define PARTOFF 13120          // per-block partial sums (<=1024)

typedef float v2f __attribute__((ext_vector_type(2)));

__host__ __device__ constexpr int gidx(int i, int j) {  // i<=j packed pair index
    return i * 8 + j - i * (i + 1) / 2;
}
__host__ __device__ constexpr int proff(int r) {        // packed row offset
    return 4 * (r / 4 + 1) * (2 * (r / 4) + (r % 4));
}

// ---------------------------------------------------------------------------
// setup1 v3 (unchanged, spill-free): lrow[] is the only register array; invLc
// column solve keeps state in LDS.
// ---------------------------------------------------------------------------
__global__ __launch_bounds__(64) void setup1_kernel(
    const float* __restrict__ mu, const float* __restrict__ L,
    float* __restrict__ ws)
{
    __shared__ float sA[D][D + 1];
    __shared__ float sLc[D][D + 1];
    __shared__ float sI[D][D + 1];
    const int k = blockIdx.x;
    const int tid = threadIdx.x;
    const int i = tid & 31;

    for (int e = tid; e < D * D; e += 64) sI[e >> 5][e & 31] = L[k * D * D + e];
    __syncthreads();

    for (int e = tid; e < D * D; e += 64) {
        const int a = e >> 5, c = e & 31;
        float s = (a == c) ? 1.0f : 0.0f;
        #pragma unroll
        for (int b = 0; b < D; ++b) s = fmaf(sI[a][b], sI[c][b], s);
        sA[a][c] = s;
    }
    __syncthreads();

    float lrow[D];
    #pragma unroll
    for (int j = 0; j < D; ++j) {
        if (i == j) {
            float s = sA[j][j];
            #pragma unroll
            for (int b = 0; b < j; ++b) s = fmaf(-lrow[b], lrow[b], s);
            const float d = sqrtf(s);
            lrow[j] = d;
            #pragma unroll
            for (int b = 0; b < j; ++b) sLc[j][b] = lrow[b];
            sLc[j][j] = d;
        }
        __syncthreads();
        if (i > j) {
            float s = sA[i][j];
            #pragma unroll
            for (int b = 0; b < j; ++b) s = fmaf(-lrow[b], sLc[j][b], s);
            lrow[j] = s / sLc[j][j];
        }
    }
    __syncthreads();

    for (int e = tid; e < D * D; e += 64) {
        const int r = e >> 5, c = e & 31;
        ws[LCOFF + k * D * D + e] = (c <= r) ? sLc[r][c] : 0.0f;
    }

    {
        const int j = i;
        #pragma unroll
        for (int ii = 0; ii < D; ++ii) {
            float s = (ii == j) ? 1.0f : 0.0f;
            #pragma unroll
            for (int b = 0; b < ii; ++b) s = fmaf(-sLc[ii][b], sI[b][j], s);
            const float cii = s / sLc[ii][ii];
            sI[ii][j] = cii;
            const int w4 = 4 * (ii / 4 + 1);
            if (j < w4) ws[PMOFF + k * PROWS + proff(ii) + j] = cii;
        }
    }
    __syncthreads();

    {
        float s = 0.0f;
        #pragma unroll
        for (int b = 0; b < D; ++b) s = fmaf(sI[i][b], mu[k * D + b], s);
        ws[WOFF + k * D + i] = s;
    }
}

// ---------------------------------------------------------------------------
// setup2 (unchanged): pair constants from staged Lc.
// ---------------------------------------------------------------------------
#define SLC(kk, r, c) sLc2[(kk) * 1024 + (r) * 32 + (c)]

__global__ __launch_bounds__(64) void setup2_kernel(
    const float* __restrict__ mu, const float* __restrict__ weights,
    float* __restrict__ ws)
{
    __shared__ float sLc2[K * D * D];
    __shared__ float sLogw[K];
    __shared__ float sCp[NPAIR];
    __shared__ float sCmax;
    const int tid = threadIdx.x;

    {
        const float4* src = (const float4*)(ws + LCOFF);
        float4* dst = (float4*)sLc2;
        for (int e = tid; e < K * D * D / 4; e += 64) dst[e] = src[e];
    }
    if (tid == 0) {
        float m = -INFINITY;
        for (int t = 0; t < K; ++t) m = fmaxf(m, weights[t]);
        float s = 0.0f;
        for (int t = 0; t < K; ++t) s += expf(weights[t] - m);
        const float lse = m + logf(s);
        for (int t = 0; t < K; ++t) sLogw[t] = weights[t] - lse;
    }
    __syncthreads();

    if (tid < NPAIR) {
        int tt = tid, pi = 0;
        while (tt >= (K - pi)) { tt -= (K - pi); ++pi; }
        const int pj = pi + tt;
        const float LOG2PI = 1.8378770664093453f;
        float sumlogS = 0.0f, logdetsig = 0.0f;
        #pragma unroll
        for (int r = 0; r < D; ++r) {
            const float di = SLC(pi, r, r), dj = SLC(pj, r, r);
            sumlogS += logf(di + dj);
            logdetsig -= logf(1.0f / di + 1.0f / dj);
        }
        float v[D];
        float quad_acc = 0.0f;
        #pragma unroll
        for (int r = 0; r < D; ++r) {
            const float d0 = mu[pi * D + r] - mu[pj * D + r];
            float s = d0;
            #pragma unroll
            for (int b = 0; b < r; ++b)
                s = fmaf(-(SLC(pi, r, b) + SLC(pj, r, b)), v[b], s);
            v[r] = s / (SLC(pi, r, r) + SLC(pj, r, r));
            quad_acc = fmaf(d0, v[r], quad_acc);
        }
        const float quad = -0.5f * quad_acc;
        float c = quad - 0.5f * sumlogS - (float)D * LOG2PI - 0.5f * logdetsig
                  + sLogw[pi] + sLogw[pj];
        if (pi < pj) c += 0.6931471805599453f;
        sCp[tid] = c;
    }
    __syncthreads();
    if (tid == 0) {
        float m = -INFINITY;
        for (int t = 0; t < NPAIR; ++t) m = fmaxf(m, sCp[t]);
        sCmax = m;
        ws[CMAXOFF] = m;
    }
    __syncthreads();
    if (tid < NPAIR)
        ws[C2OFF + tid] = (sCp[tid] - sCmax) * 1.4426950408889634f;
}

// ---------------------------------------------------------------------------
// main v8: 256-thr block = 4 waves covering the SAME 128 samples (S=2/lane);
// wave w computes rh in {w, 7-w} (288 b128 each, perfectly balanced).
// Grid 1024 -> 4 blocks/CU -> 16 waves/CU (4/SIMD) at VGPR<=128.
// Gram combine: 3 sequential exchange rounds through the reused M buffer.
// ---------------------------------------------------------------------------
#define XCHF 4680   // floats needed for exchange (36*65 float2) <= reuse area

__global__ __launch_bounds__(256, 2) void main_kernel(
    const float* __restrict__ X, const float* __restrict__ cst,
    float* __restrict__ partials, int nsamp)
{
    __shared__ __align__(16) float sBig[XCHF];   // packed M (4608f) / G-exchange
    __shared__ __align__(16) float sW[K * D];
    __shared__ float sC2[NPAIR];
    const int tid = threadIdx.x;
    const int wv = tid >> 6;        // wave id 0..3
    const int lane = tid & 63;

    const int n0 = blockIdx.x * 128 + lane;
    const int n1 = n0 + 64;
    const int m0 = (n0 < nsamp) ? n0 : 0;     // branchless clamps
    const int m1 = (n1 < nsamp) ? n1 : 0;

    // x for both samples, column-pair packed
    v2f xa[16], xb[16];
    {
        const float4* Xv0 = (const float4*)(X + m0 * D);
        const float4* Xv1 = (const float4*)(X + m1 * D);
        #pragma unroll
        for (int q = 0; q < 8; ++q) {
            const float4 t0 = Xv0[q];
            xa[2 * q]     = (v2f){t0.x, t0.y};
            xa[2 * q + 1] = (v2f){t0.z, t0.w};
            const float4 t1 = Xv1[q];
            xb[2 * q]     = (v2f){t1.x, t1.y};
            xb[2 * q + 1] = (v2f){t1.z, t1.w};
        }
    }

    {   // stage packed M + w + c2 into LDS
        const float4* src = (const float4*)cst;
        float4* dst = (float4*)sBig;
        for (int e = tid; e < K * PROWS / 4; e += 256) dst[e] = src[e];
        const float4* srcw = (const float4*)(cst + WOFF);
        float4* dstw = (float4*)sW;
        if (tid < K * D / 4) dstw[tid] = srcw[tid];
        if (tid < NPAIR) sC2[tid] = cst[C2OFF + tid];
    }
    __syncthreads();

    v2f G2[NPAIR];   // this wave's PARTIAL Gram (rows with rh in {wv, 7-wv})
    #pragma unroll
    for (int t = 0; t < NPAIR; ++t) G2[t] = (v2f){0.0f, 0.0f};

    #pragma unroll
    for (int rh = 0; rh < 8; ++rh) {
        if (rh == wv || rh == 7 - wv) {     // wave-uniform gate, balanced split
            #pragma unroll
            for (int rr = 0; rr < 4; ++rr) {
                const int r = 4 * rh + rr;
                v2f ya[K], yb[K];
                #pragma unroll
                for (int k = 0; k < K; ++k) {
                    const float wvv = sW[k * D + r];
                    v2f a0 = (v2f){-wvv, 0.0f};
                    v2f a1 = (v2f){-wvv, 0.0f};
                    const float* Mr = sBig + k * PROWS + proff(r);
                    #pragma unroll
                    for (int c4 = 0; c4 <= rh; ++c4) {
                        const float4 m4 = *(const float4*)(Mr + 4 * c4);
                        const v2f mlo = (v2f){m4.x, m4.y};   // natural reg pairs
                        const v2f mhi = (v2f){m4.z, m4.w};
                        a0 = __builtin_elementwise_fma(mlo, xa[2 * c4],     a0);
                        a1 = __builtin_elementwise_fma(mlo, xb[2 * c4],     a1);
                        a0 = __builtin_elementwise_fma(mhi, xa[2 * c4 + 1], a0);
                        a1 = __builtin_elementwise_fma(mhi, xb[2 * c4 + 1], a1);
                    }
                    ya[k] = a0;  yb[k] = a1;
                }
                v2f y2[K];
                #pragma unroll
                for (int k = 0; k < K; ++k)
                    y2[k] = (v2f){ya[k].x + ya[k].y, yb[k].x + yb[k].y};
                #pragma unroll
                for (int pi = 0; pi < K; ++pi)
                    #pragma unroll
                    for (int pj = pi; pj < K; ++pj)
                        G2[gidx(pi, pj)] = __builtin_elementwise_fma(
                            y2[pi], y2[pj], G2[gidx(pi, pj)]);
            }
        }
    }

    __syncthreads();   // all M reads complete; sBig reusable for exchange

    // 3 sequential combine rounds: wave p publishes, wave 0 accumulates.
    // float2 element at xch[t*65 + lane] (stride 65 -> conflict-free).
    float2* xch = (float2*)sBig;
    #pragma unroll
    for (int p = 1; p < 4; ++p) {
        if (wv == p) {
            #pragma unroll
            for (int t = 0; t < NPAIR; ++t)
                xch[t * 65 + lane] = make_float2(G2[t].x, G2[t].y);
        }
        __syncthreads();
        if (wv == 0) {
            #pragma unroll
            for (int t = 0; t < NPAIR; ++t) {
                const float2 g = xch[t * 65 + lane];
                G2[t] += (v2f){g.x, g.y};
            }
        }
        __syncthreads();
    }

    // wave 0: 36-term exp sum for both samples, reduce, store
    if (wv == 0) {
        v2f acc2 = (v2f){0.0f, 0.0f};
        const float NH = -0.72134752044448170f;   // -0.5*log2(e)
        #pragma unroll
        for (int pi = 0; pi < K; ++pi)
            #pragma unroll
            for (int pj = pi; pj < K; ++pj) {
                const v2f q2 = __builtin_elementwise_fma(
                    (v2f){2.0f, 2.0f}, G2[gidx(pi, pj)],
                    G2[gidx(pi, pi)] + G2[gidx(pj, pj)]);
                const float c = sC2[gidx(pi, pj)];
                const v2f e2 = __builtin_elementwise_fma((v2f){NH, NH}, q2,
                                                         (v2f){c, c});
                acc2.x += exp2f(e2.x);
                acc2.y += exp2f(e2.y);
            }
        float acc = ((n0 < nsamp) ? acc2.x : 0.0f)
                  + ((n1 < nsamp) ? acc2.y : 0.0f);

        #pragma unroll
        for (int s = 1; s < 64; s <<= 1) acc += __shfl_xor(acc, s, 64);
        if (lane == 0) partials[blockIdx.x] = acc;
    }
}

__global__ __launch_bounds__(256) void finish_kernel(
    const float* __restrict__ partials, const float* __restrict__ ws,
    float* __restrict__ out, int nblk)
{
    __shared__ float sRed[4];
    const int tid = threadIdx.x;
    float acc = 0.0f;
    for (int e = tid; e < nblk; e += 256) acc += partials[e];
    #pragma unroll
    for (int s = 1; s < 64; s <<= 1) acc += __shfl_xor(acc, s, 64);
    if ((tid & 63) == 0) sRed[tid >> 6] = acc;
    __syncthreads();
    if (tid == 0) out[0] = ws[CMAXOFF] + logf(sRed[0] + sRed[1] + sRed[2] + sRed[3]);
}

extern "C" void kernel_launch(void* const* d_in, const int* in_sizes, int n_in,
                              void* d_out, int out_size, void* d_ws, size_t ws_size,
                              hipStream_t stream) {
    const float* X = (const float*)d_in[0];
    const float* mu = (const float*)d_in[1];
    const float* L = (const float*)d_in[2];
    const float* w = (const float*)d_in[3];
    float* wsf = (float*)d_ws;
    float* out = (float*)d_out;

    const int nsamp = in_sizes[0] / D;
    const int nblk = (nsamp + 127) / 128;   // 128 samples per 4-wave block

    setup1_kernel<<<K, 64, 0, stream>>>(mu, L, wsf);
    setup2_kernel<<<1, 64, 0, stream>>>(mu, w, wsf);
    main_kernel<<<nblk, 256, 0, stream>>>(X, wsf, wsf + PARTOFF, nsamp);
    finish_kernel<<<1, 256, 0, stream>>>(wsf + PARTOFF, wsf, out, nblk);
}

// Round 12
// 138.583 us; speedup vs baseline: 1.9892x; 1.9892x over previous
//
#include <hip/hip_runtime.h>

// Problem constants
#define D 32
#define K 8
#define NPAIR 36
#define PROWS 576              // packed (4-padded triangular) floats per matrix

// ws layout (float offsets)
#define PMOFF 0                // packed invLc, 8 x 576
#define WOFF 4608              // w_k = invLc_k mu_k, 8 x 32
#define C2OFF 4864             // (c'_t - cmax) * log2(e), 36
#define CMAXOFF 4900
#define LCOFF 4928             // Lc (cholesky factors), 8 x 32 x 32, upper zeroed
#define PARTOFF 13120          // per-block partial sums (<=1024)

typedef float v2f __attribute__((ext_vector_type(2)));

__host__ __device__ constexpr int gidx(int i, int j) {  // i<=j packed pair index
    return i * 8 + j - i * (i + 1) / 2;
}
__host__ __device__ constexpr int proff(int r) {        // packed row offset
    return 4 * (r / 4 + 1) * (2 * (r / 4) + (r % 4));
}

// ---------------------------------------------------------------------------
// setup1 v3 (unchanged, spill-free): lrow[] is the only register array; invLc
// column solve keeps state in LDS.
// ---------------------------------------------------------------------------
__global__ __launch_bounds__(64) void setup1_kernel(
    const float* __restrict__ mu, const float* __restrict__ L,
    float* __restrict__ ws)
{
    __shared__ float sA[D][D + 1];
    __shared__ float sLc[D][D + 1];
    __shared__ float sI[D][D + 1];
    const int k = blockIdx.x;
    const int tid = threadIdx.x;
    const int i = tid & 31;

    for (int e = tid; e < D * D; e += 64) sI[e >> 5][e & 31] = L[k * D * D + e];
    __syncthreads();

    for (int e = tid; e < D * D; e += 64) {
        const int a = e >> 5, c = e & 31;
        float s = (a == c) ? 1.0f : 0.0f;
        #pragma unroll
        for (int b = 0; b < D; ++b) s = fmaf(sI[a][b], sI[c][b], s);
        sA[a][c] = s;
    }
    __syncthreads();

    float lrow[D];
    #pragma unroll
    for (int j = 0; j < D; ++j) {
        if (i == j) {
            float s = sA[j][j];
            #pragma unroll
            for (int b = 0; b < j; ++b) s = fmaf(-lrow[b], lrow[b], s);
            const float d = sqrtf(s);
            lrow[j] = d;
            #pragma unroll
            for (int b = 0; b < j; ++b) sLc[j][b] = lrow[b];
            sLc[j][j] = d;
        }
        __syncthreads();
        if (i > j) {
            float s = sA[i][j];
            #pragma unroll
            for (int b = 0; b < j; ++b) s = fmaf(-lrow[b], sLc[j][b], s);
            lrow[j] = s / sLc[j][j];
        }
    }
    __syncthreads();

    for (int e = tid; e < D * D; e += 64) {
        const int r = e >> 5, c = e & 31;
        ws[LCOFF + k * D * D + e] = (c <= r) ? sLc[r][c] : 0.0f;
    }

    {
        const int j = i;
        #pragma unroll
        for (int ii = 0; ii < D; ++ii) {
            float s = (ii == j) ? 1.0f : 0.0f;
            #pragma unroll
            for (int b = 0; b < ii; ++b) s = fmaf(-sLc[ii][b], sI[b][j], s);
            const float cii = s / sLc[ii][ii];
            sI[ii][j] = cii;
            const int w4 = 4 * (ii / 4 + 1);
            if (j < w4) ws[PMOFF + k * PROWS + proff(ii) + j] = cii;
        }
    }
    __syncthreads();

    {
        float s = 0.0f;
        #pragma unroll
        for (int b = 0; b < D; ++b) s = fmaf(sI[i][b], mu[k * D + b], s);
        ws[WOFF + k * D + i] = s;
    }
}

// ---------------------------------------------------------------------------
// setup2 v2: 256-thread block. ALL global inputs (Lc 32KB, mu 1KB, weights)
// staged into LDS cooperatively (coalesced, 4 waves hide latency) BEFORE the
// 36-thread solve touches anything -- removes the 64 scattered 4B global
// loads that sat in the solve's dependency chain (the hidden ~40-80 us).
// ---------------------------------------------------------------------------
#define SLC(kk, r, c) sLc2[(kk) * 1024 + (r) * 32 + (c)]

__global__ __launch_bounds__(256) void setup2_kernel(
    const float* __restrict__ mu, const float* __restrict__ weights,
    float* __restrict__ ws)
{
    __shared__ float sLc2[K * D * D];   // 32 KB
    __shared__ float sMu[K * D];
    __shared__ float sWt[K];
    __shared__ float sLogw[K];
    __shared__ float sCp[NPAIR];
    __shared__ float sCmax;
    const int tid = threadIdx.x;

    {   // stage everything: 8 float4/thread for Lc, 1 float/thread for mu
        const float4* src = (const float4*)(ws + LCOFF);
        float4* dst = (float4*)sLc2;
        #pragma unroll
        for (int e = 0; e < 8; ++e) dst[tid + 256 * e] = src[tid + 256 * e];
        sMu[tid] = mu[tid];
        if (tid < K) sWt[tid] = weights[tid];
    }
    __syncthreads();

    if (tid == 0) {   // log-softmax of weights (from LDS)
        float m = -INFINITY;
        for (int t = 0; t < K; ++t) m = fmaxf(m, sWt[t]);
        float s = 0.0f;
        for (int t = 0; t < K; ++t) s += expf(sWt[t] - m);
        const float lse = m + logf(s);
        for (int t = 0; t < K; ++t) sLogw[t] = sWt[t] - lse;
    }
    __syncthreads();

    if (tid < NPAIR) {
        int tt = tid, pi = 0;
        while (tt >= (K - pi)) { tt -= (K - pi); ++pi; }
        const int pj = pi + tt;
        const float LOG2PI = 1.8378770664093453f;
        float sumlogS = 0.0f, logdetsig = 0.0f;
        #pragma unroll
        for (int r = 0; r < D; ++r) {
            const float di = SLC(pi, r, r), dj = SLC(pj, r, r);
            sumlogS += logf(di + dj);
            logdetsig -= logf(1.0f / di + 1.0f / dj);   // diag(M) = 1/di + 1/dj
        }
        float v[D];
        float quad_acc = 0.0f;
        #pragma unroll
        for (int r = 0; r < D; ++r) {
            const float d0 = sMu[pi * D + r] - sMu[pj * D + r];
            float s = d0;
            #pragma unroll
            for (int b = 0; b < r; ++b)
                s = fmaf(-(SLC(pi, r, b) + SLC(pj, r, b)), v[b], s);
            v[r] = s / (SLC(pi, r, r) + SLC(pj, r, r));
            quad_acc = fmaf(d0, v[r], quad_acc);
        }
        const float quad = -0.5f * quad_acc;
        float c = quad - 0.5f * sumlogS - (float)D * LOG2PI - 0.5f * logdetsig
                  + sLogw[pi] + sLogw[pj];
        if (pi < pj) c += 0.6931471805599453f;   // off-diagonal multiplicity 2
        sCp[tid] = c;
    }
    __syncthreads();
    if (tid == 0) {
        float m = -INFINITY;
        for (int t = 0; t < NPAIR; ++t) m = fmaxf(m, sCp[t]);
        sCmax = m;
        ws[CMAXOFF] = m;
    }
    __syncthreads();
    if (tid < NPAIR)
        ws[C2OFF + tid] = (sCp[tid] - sCmax) * 1.4426950408889634f;
}

// ---------------------------------------------------------------------------
// main v7 (R10 winner, verbatim): 128-thr block = 2 waves covering the SAME
// 128 samples (S=2/lane); wave 0 even rh, wave 1 odd rh. Wave 1 publishes its
// partial Gram via LDS; wave 0 combines + epilogue. 8 waves/CU (2/SIMD),
// ~576 broadcast b128 per wave.
// ---------------------------------------------------------------------------
#define XCHG 4864   // float2-exchange area reuses sBig after M reads complete

__global__ __launch_bounds__(128, 2) void main_kernel(
    const float* __restrict__ X, const float* __restrict__ cst,
    float* __restrict__ partials, int nsamp)
{
    __shared__ __align__(16) float sBig[XCHG];   // packed M (4608f) / G-exchange
    __shared__ __align__(16) float sW[K * D];
    __shared__ float sC2[NPAIR];
    const int tid = threadIdx.x;
    const int wv = tid >> 6;        // wave id within block
    const int lane = tid & 63;

    const int n0 = blockIdx.x * 128 + lane;
    const int n1 = n0 + 64;
    const int m0 = (n0 < nsamp) ? n0 : 0;     // branchless clamps
    const int m1 = (n1 < nsamp) ? n1 : 0;

    // x for both samples, column-pair packed
    v2f xa[16], xb[16];
    {
        const float4* Xv0 = (const float4*)(X + m0 * D);
        const float4* Xv1 = (const float4*)(X + m1 * D);
        #pragma unroll
        for (int q = 0; q < 8; ++q) {
            const float4 t0 = Xv0[q];
            xa[2 * q]     = (v2f){t0.x, t0.y};
            xa[2 * q + 1] = (v2f){t0.z, t0.w};
            const float4 t1 = Xv1[q];
            xb[2 * q]     = (v2f){t1.x, t1.y};
            xb[2 * q + 1] = (v2f){t1.z, t1.w};
        }
    }

    {   // stage packed M + w + c2 into LDS
        const float4* src = (const float4*)cst;
        float4* dst = (float4*)sBig;
        for (int e = tid; e < K * PROWS / 4; e += 128) dst[e] = src[e];
        const float4* srcw = (const float4*)(cst + WOFF);
        float4* dstw = (float4*)sW;
        if (tid < K * D / 4) dstw[tid] = srcw[tid];
        if (tid < NPAIR) sC2[tid] = cst[C2OFF + tid];
    }
    __syncthreads();

    v2f G2[NPAIR];   // this wave's PARTIAL Gram (rows with rh%2 == wv)
    #pragma unroll
    for (int t = 0; t < NPAIR; ++t) G2[t] = (v2f){0.0f, 0.0f};

    #pragma unroll
    for (int rh = 0; rh < 8; ++rh) {
        if ((rh & 1) == wv) {               // wave-uniform gate
            #pragma unroll
            for (int rr = 0; rr < 4; ++rr) {
                const int r = 4 * rh + rr;
                v2f ya[K], yb[K];
                #pragma unroll
                for (int k = 0; k < K; ++k) {
                    const float wvv = sW[k * D + r];
                    v2f a0 = (v2f){-wvv, 0.0f};
                    v2f a1 = (v2f){-wvv, 0.0f};
                    const float* Mr = sBig + k * PROWS + proff(r);
                    #pragma unroll
                    for (int c4 = 0; c4 <= rh; ++c4) {
                        const float4 m4 = *(const float4*)(Mr + 4 * c4);
                        const v2f mlo = (v2f){m4.x, m4.y};   // natural reg pairs
                        const v2f mhi = (v2f){m4.z, m4.w};
                        a0 = __builtin_elementwise_fma(mlo, xa[2 * c4],     a0);
                        a1 = __builtin_elementwise_fma(mlo, xb[2 * c4],     a1);
                        a0 = __builtin_elementwise_fma(mhi, xa[2 * c4 + 1], a0);
                        a1 = __builtin_elementwise_fma(mhi, xb[2 * c4 + 1], a1);
                    }
                    ya[k] = a0;  yb[k] = a1;
                }
                v2f y2[K];
                #pragma unroll
                for (int k = 0; k < K; ++k)
                    y2[k] = (v2f){ya[k].x + ya[k].y, yb[k].x + yb[k].y};
                #pragma unroll
                for (int pi = 0; pi < K; ++pi)
                    #pragma unroll
                    for (int pj = pi; pj < K; ++pj)
                        G2[gidx(pi, pj)] = __builtin_elementwise_fma(
                            y2[pi], y2[pj], G2[gidx(pi, pj)]);
            }
        }
    }

    __syncthreads();   // all M reads complete; sBig reusable for exchange

    // wave 1 publishes partial Gram: float2 element at index t*65 + lane
    if (wv == 1) {
        float2* xch = (float2*)sBig;
        #pragma unroll
        for (int t = 0; t < NPAIR; ++t)
            xch[t * 65 + lane] = make_float2(G2[t].x, G2[t].y);
    }
    __syncthreads();

    // wave 0: combine, 36-term exp sum for both samples, reduce, store
    if (wv == 0) {
        const float2* xch = (const float2*)sBig;
        #pragma unroll
        for (int t = 0; t < NPAIR; ++t) {
            const float2 g = xch[t * 65 + lane];
            G2[t] += (v2f){g.x, g.y};
        }

        v2f acc2 = (v2f){0.0f, 0.0f};
        const float NH = -0.72134752044448170f;   // -0.5*log2(e)
        #pragma unroll
        for (int pi = 0; pi < K; ++pi)
            #pragma unroll
            for (int pj = pi; pj < K; ++pj) {
                const v2f q2 = __builtin_elementwise_fma(
                    (v2f){2.0f, 2.0f}, G2[gidx(pi, pj)],
                    G2[gidx(pi, pi)] + G2[gidx(pj, pj)]);
                const float c = sC2[gidx(pi, pj)];
                const v2f e2 = __builtin_elementwise_fma((v2f){NH, NH}, q2,
                                                         (v2f){c, c});
                acc2.x += exp2f(e2.x);
                acc2.y += exp2f(e2.y);
            }
        float acc = ((n0 < nsamp) ? acc2.x : 0.0f)
                  + ((n1 < nsamp) ? acc2.y : 0.0f);

        #pragma unroll
        for (int s = 1; s < 64; s <<= 1) acc += __shfl_xor(acc, s, 64);
        if (lane == 0) partials[blockIdx.x] = acc;
    }
}

__global__ __launch_bounds__(256) void finish_kernel(
    const float* __restrict__ partials, const float* __restrict__ ws,
    float* __restrict__ out, int nblk)
{
    __shared__ float sRed[4];
    const int tid = threadIdx.x;
    float acc = 0.0f;
    for (int e = tid; e < nblk; e += 256) acc += partials[e];
    #pragma unroll
    for (int s = 1; s < 64; s <<= 1) acc += __shfl_xor(acc, s, 64);
    if ((tid & 63) == 0) sRed[tid >> 6] = acc;
    __syncthreads();
    if (tid == 0) out[0] = ws[CMAXOFF] + logf(sRed[0] + sRed[1] + sRed[2] + sRed[3]);
}

extern "C" void kernel_launch(void* const* d_in, const int* in_sizes, int n_in,
                              void* d_out, int out_size, void* d_ws, size_t ws_size,
                              hipStream_t stream) {
    const float* X = (const float*)d_in[0];
    const float* mu = (const float*)d_in[1];
    const float* L = (const float*)d_in[2];
    const float* w = (const float*)d_in[3];
    float* wsf = (float*)d_ws;
    float* out = (float*)d_out;

    const int nsamp = in_sizes[0] / D;
    const int nblk = (nsamp + 127) / 128;   // 128 samples per 2-wave block

    setup1_kernel<<<K, 64, 0, stream>>>(mu, L, wsf);
    setup2_kernel<<<1, 256, 0, stream>>>(mu, w, wsf);
    main_kernel<<<nblk, 128, 0, stream>>>(X, wsf, wsf + PARTOFF, nsamp);
    finish_kernel<<<1, 256, 0, stream>>>(wsf + PARTOFF, wsf, out, nblk);
}